// Round 6
// baseline (408.152 us; speedup 1.0000x reference)
//
#include <hip/hip_runtime.h>
#include <hip/hip_bf16.h>

typedef __bf16 bf16_t;
typedef __bf16 bf16x4 __attribute__((ext_vector_type(4)));
typedef __bf16 bf16x8 __attribute__((ext_vector_type(8)));
typedef float f32x4 __attribute__((ext_vector_type(4)));

#define B_    2
#define T_    2048
#define DIM_  2048
#define H_    16
#define HKV_  4
#define D_    128
#define KVDIM_ 512

// ---- helpers --------------------------------------------------------------
__device__ __forceinline__ bf16x8 cvt8(f32x4 a, f32x4 b) {
  bf16x8 r;
  r[0] = (bf16_t)a[0]; r[1] = (bf16_t)a[1]; r[2] = (bf16_t)a[2]; r[3] = (bf16_t)a[3];
  r[4] = (bf16_t)b[0]; r[5] = (bf16_t)b[1]; r[6] = (bf16_t)b[2]; r[7] = (bf16_t)b[3];
  return r;
}
__device__ __forceinline__ bf16x4 cvt4(f32x4 a) {
  bf16x4 r;
  r[0] = (bf16_t)a[0]; r[1] = (bf16_t)a[1]; r[2] = (bf16_t)a[2]; r[3] = (bf16_t)a[3];
  return r;
}
// async global->LDS, 16B per lane; LDS dest = wave-uniform base + lane*16
__device__ __forceinline__ void g2l16(const void* g, void* l) {
  __builtin_amdgcn_global_load_lds(
      (const __attribute__((address_space(1))) unsigned int*)g,
      (__attribute__((address_space(3))) unsigned int*)l, 16, 0, 0);
}

// ---------------------------------------------------------------------------
// Fused fp32 -> bf16 convert (one launch).  2048-elem blocks.
// x:4096 | Wq:2048 | Wk:512 | Wv:512 | Wp:2048  (Wq/Wk/Wv -> contiguous Wqkvb)
// ---------------------------------------------------------------------------
__global__ __launch_bounds__(256)
void cvt_all(const float* __restrict__ x,  const float* __restrict__ wq,
             const float* __restrict__ wk, const float* __restrict__ wv,
             const float* __restrict__ wp, bf16_t* __restrict__ xb,
             bf16_t* __restrict__ wqkvb, bf16_t* __restrict__ wpb) {
  int blk = blockIdx.x;
  const float* s; bf16_t* d; int lb;
  if (blk < 4096)      { s = x;  d = xb;                              lb = blk; }
  else if (blk < 6144) { s = wq; d = wqkvb;                           lb = blk - 4096; }
  else if (blk < 6656) { s = wk; d = wqkvb + (size_t)2048 * DIM_;     lb = blk - 6144; }
  else if (blk < 7168) { s = wv; d = wqkvb + (size_t)2560 * DIM_;     lb = blk - 6656; }
  else                 { s = wp; d = wpb;                             lb = blk - 7168; }
  size_t i = (size_t)lb * 2048 + (size_t)threadIdx.x * 8;
  f32x4 a = *(const f32x4*)(s + i);
  f32x4 b = *(const f32x4*)(s + i + 4);
  *(bf16x8*)(d + i) = cvt8(a, b);
}

// ---------------------------------------------------------------------------
// GEMM: C[M,N] = A[M,K] @ W[N,K]^T  (bf16 MFMA, fp32 accum), 128x128 tile,
// BK=32, 4 waves each computing a 64x64 sub-tile.  K compile-time (KK) for
// address strength-reduction; staging pointers hoisted; unroll 2.
// MODE 0: C bf16.  MODE 2: C fp32.
// MODE 1: fused QKV epilogue -- col<2048 -> Cb(Q); col<2560 -> Kb; else Vb+Vf.
// MODE 3: fallback KV epilogue (fp32 W via Wg/Wg2): col<512 -> Cb(K); else V.
// ---------------------------------------------------------------------------
template <int MODE, bool AASYNC, bool WASYNC, int KK>
__global__ __launch_bounds__(256)
void gemm128(const void* __restrict__ Ag, const void* __restrict__ Wg,
             const void* __restrict__ Wg2, void* __restrict__ Cb,
             bf16_t* __restrict__ Kb, bf16_t* __restrict__ Vb,
             float* __restrict__ Vf, int M, int N) {
  constexpr int LDA = AASYNC ? 32 : 40;
  constexpr int LDW = WASYNC ? 32 : 40;
  __shared__ bf16_t As[128 * LDA];
  __shared__ bf16_t Ws[128 * LDW];
  const int tid  = threadIdx.x;
  const int wave = tid >> 6, lane = tid & 63;
  const int l16  = lane & 15, lg = lane >> 4;
  const int m0 = blockIdx.y * 128, n0 = blockIdx.x * 128;
  const int wm = (wave & 1) * 64, wn = (wave >> 1) * 64;
  f32x4 acc[4][4] = {};

  // hoisted staging pointers (async paths)
  const int r4 = lane >> 2, c8 = (lane & 3) * 8;
  const bf16_t* ap0 = (const bf16_t*)Ag + (size_t)(m0 + wave * 32 + r4) * KK + c8;
  const bf16_t* ap1 = ap0 + (size_t)16 * KK;
  const bf16_t* wpa = (const bf16_t*)Wg + (size_t)(n0 + wave * 32 + r4) * KK + c8;
  const bf16_t* wpb2 = wpa + (size_t)16 * KK;
  bf16_t* lda0 = &As[(wave * 32) * LDA];
  bf16_t* lda1 = &As[(wave * 32 + 16) * LDA];
  bf16_t* ldw0 = &Ws[(wave * 32) * LDW];
  bf16_t* ldw1 = &Ws[(wave * 32 + 16) * LDW];

#pragma unroll 2
  for (int k0 = 0; k0 < KK; k0 += 32) {
    __syncthreads();
    if constexpr (AASYNC) {
      g2l16(ap0 + k0, lda0);
      g2l16(ap1 + k0, lda1);
    } else {
      const float* A = (const float*)Ag;
#pragma unroll
      for (int j = 0; j < 4; j++) {
        int row = wave * 32 + j * 8 + (lane >> 3);
        int cf  = (lane & 7) * 4;
        f32x4 v = *(const f32x4*)&A[(size_t)(m0 + row) * KK + k0 + cf];
        *(bf16x4*)&As[row * LDA + cf] = cvt4(v);
      }
    }
    if constexpr (WASYNC) {
      g2l16(wpa + k0, ldw0);
      g2l16(wpb2 + k0, ldw1);
    } else {
      const float* W;
      int nb;
      if constexpr (MODE == 3) {
        if (n0 < 512) { W = (const float*)Wg;  nb = n0; }
        else          { W = (const float*)Wg2; nb = n0 - 512; }
      } else { W = (const float*)Wg; nb = n0; }
#pragma unroll
      for (int j = 0; j < 4; j++) {
        int row = wave * 32 + j * 8 + (lane >> 3);
        int cf  = (lane & 7) * 4;
        f32x4 v = *(const f32x4*)&W[(size_t)(nb + row) * KK + k0 + cf];
        *(bf16x4*)&Ws[row * LDW + cf] = cvt4(v);
      }
    }
    __syncthreads();
    bf16x8 af[4], bfr[4];
#pragma unroll
    for (int i = 0; i < 4; i++)
      af[i] = *(const bf16x8*)&As[(wm + i * 16 + l16) * LDA + lg * 8];
#pragma unroll
    for (int j = 0; j < 4; j++)
      bfr[j] = *(const bf16x8*)&Ws[(wn + j * 16 + l16) * LDW + lg * 8];
#pragma unroll
    for (int i = 0; i < 4; i++)
#pragma unroll
      for (int j = 0; j < 4; j++)
        acc[i][j] = __builtin_amdgcn_mfma_f32_16x16x32_bf16(af[i], bfr[j], acc[i][j], 0, 0, 0);
  }
#pragma unroll
  for (int i = 0; i < 4; i++)
#pragma unroll
    for (int j = 0; j < 4; j++) {
      int row = m0 + wm + i * 16 + lg * 4;
      int col = n0 + wn + j * 16 + l16;
#pragma unroll
      for (int r = 0; r < 4; r++) {
        float v = acc[i][j][r];
        if constexpr (MODE == 0) {
          ((bf16_t*)Cb)[(size_t)(row + r) * N + col] = (bf16_t)v;
        } else if constexpr (MODE == 2) {
          ((float*)Cb)[(size_t)(row + r) * N + col] = v;
        } else if constexpr (MODE == 1) {
          if (col < 2048)      ((bf16_t*)Cb)[(size_t)(row + r) * 2048 + col] = (bf16_t)v;
          else if (col < 2560) Kb[(size_t)(row + r) * 512 + (col - 2048)] = (bf16_t)v;
          else {
            int c = col - 2560;
            Vb[(size_t)(row + r) * 512 + c] = (bf16_t)v;
            Vf[(size_t)(row + r) * 512 + c] = v;
          }
        } else {  // MODE 3
          if (col < 512) ((bf16_t*)Cb)[(size_t)(row + r) * 512 + col] = (bf16_t)v;
          else {
            int c = col - 512;
            Vb[(size_t)(row + r) * 512 + c] = (bf16_t)v;
            Vf[(size_t)(row + r) * 512 + c] = v;
          }
        }
      }
    }
}

// ---------------------------------------------------------------------------
// Fused QK RMSNorm + NTK RoPE (+ q gain).  One wave per 128-elem head row.
// ---------------------------------------------------------------------------
__global__ __launch_bounds__(256)
void qk_norm_rope(bf16_t* __restrict__ Qp, bf16_t* __restrict__ Kp,
                  const float* __restrict__ gain) {
  const int lane = threadIdx.x & 63;
  int row = blockIdx.x * 4 + (threadIdx.x >> 6);
  bf16_t* Xp; int nh; bool ag;
  const int MQ = B_ * T_ * H_;
  if (row < MQ) { Xp = Qp; nh = H_;  ag = true; }
  else          { Xp = Kp; nh = HKV_; ag = false; row -= MQ; }
  const int h = row % nh;
  const int t = (row / nh) % T_;
  bf16_t* p = Xp + (size_t)row * D_;
  float x0 = (float)p[lane * 2 + 0];
  float x1 = (float)p[lane * 2 + 1];
  float ss = x0 * x0 + x1 * x1;
#pragma unroll
  for (int m = 32; m >= 1; m >>= 1) ss += __shfl_xor(ss, m);
  const float rn = rsqrtf(ss * (1.0f / 128.0f) + 1.1920929e-07f);
  x0 *= rn; x1 *= rn;
  const float y0 = __shfl_xor(x0, 32);
  const float y1 = __shfl_xor(x1, 32);
  const int i0 = (lane & 31) * 2;
  const float kfreq = -0.22349352180347601f;  // -log2(1e4*2^(128/126))/64
  float s0, c0, s1, c1;
  float a0 = (float)t * exp2f(kfreq * (float)i0);
  float a1 = (float)t * exp2f(kfreq * (float)(i0 + 1));
  sincosf(a0, &s0, &c0);
  sincosf(a1, &s1, &c1);
  float o0, o1;
  if (lane < 32) { o0 = x0 * c0 + y0 * s0;  o1 = x1 * c1 + y1 * s1; }
  else           { o0 = x0 * c0 - y0 * s0;  o1 = x1 * c1 - y1 * s1; }
  if (ag) { float g = gain[h]; o0 *= g; o1 *= g; }
  p[lane * 2 + 0] = (bf16_t)o0;
  p[lane * 2 + 1] = (bf16_t)o1;
}

// ---------------------------------------------------------------------------
// Causal GQA flash attention v5 — unpaired, oversubscribed.
// 1024 blocks: one 64-row q-tile each (4 waves x 16 rows); block ti does
// ti+1 K-iterations of 64 keys; causal imbalance absorbed by 3-blocks/CU
// occupancy + dispatch refill.  Global->VGPR prefetch pipeline kept.
// Static-max softmax (RMS-normed q,k -> |s| <= sqrt(128)*gain).
// ---------------------------------------------------------------------------
#define KLD 136  // K tile row stride (bf16): 128+8
#define VLD 72   // V^T tile row stride (bf16): 64+8
#define PLD 68   // P scratch row stride (fp32): 64+4

__global__ __launch_bounds__(256, 3)
void flash_attn(const bf16_t* __restrict__ Q, const bf16_t* __restrict__ Kg,
                const bf16_t* __restrict__ V, bf16_t* __restrict__ Y) {
  __shared__ bf16_t Ks[64 * KLD];      // 17408 B
  __shared__ bf16_t Vs[D_ * VLD];      // 18432 B [dim][key] transposed
  __shared__ float  Ps[4][16 * PLD];   // 17408 B per-wave P scratch
  const int tid  = threadIdx.x;
  const int wave = tid >> 6, lane = tid & 63;
  const int l16  = lane & 15, lg = lane >> 4;
  const int b = blockIdx.z, h = blockIdx.y;
  const int ti = blockIdx.x;           // q-tile 0..31
  const int hk = h >> 2;               // G = 4
  const int qrow = 64 * ti + 16 * wave;

  bf16x8 qf[4];
#pragma unroll
  for (int kk = 0; kk < 4; kk++)
    qf[kk] = *(const bf16x8*)&Q[(((size_t)b * T_ + qrow + l16) * H_ + h) * D_ + kk * 32 + lg * 8];

  f32x4 o[8] = {};
  float lsum[4] = {};
  const float C = 0.12752531f;  // (1/sqrt(128)) * log2(e)

  // staging coords
  const int sr = tid >> 4, sc = (tid & 15) * 8;  // K: rows sr+16j
  const int sp2 = (tid & 31) * 2;                // V: key pair
  const int dvh = (tid >> 5) * 8;                // V: dim chunk base

  bf16x8 kreg[4];
  bf16x8 vreg[2][2];
  auto pf_load = [&](int k0) {
#pragma unroll
    for (int j = 0; j < 4; j++)
      kreg[j] = *(const bf16x8*)&Kg[(((size_t)b * T_ + k0 + sr + 16 * j) * HKV_ + hk) * D_ + sc];
#pragma unroll
    for (int it = 0; it < 2; it++) {
      const bf16_t* vb = &V[(((size_t)b * T_ + k0 + sp2) * HKV_ + hk) * D_ + dvh + it * 64];
      vreg[it][0] = *(const bf16x8*)vb;
      vreg[it][1] = *(const bf16x8*)(vb + HKV_ * D_);
    }
  };
  auto pf_store = [&]() {
#pragma unroll
    for (int j = 0; j < 4; j++)
      *(bf16x8*)&Ks[(sr + 16 * j) * KLD + sc] = kreg[j];
#pragma unroll
    for (int it = 0; it < 2; it++) {
      int dd = dvh + it * 64;
      const unsigned short* au = (const unsigned short*)&vreg[it][0];
      const unsigned short* bu = (const unsigned short*)&vreg[it][1];
#pragma unroll
      for (int i = 0; i < 8; i++) {
        unsigned int pr = (unsigned int)au[i] | ((unsigned int)bu[i] << 16);
        *(unsigned int*)&Vs[(dd + i) * VLD + sp2] = pr;
      }
    }
  };

  const int nkb = ti + 1;
  pf_load(0);
  for (int kb = 0; kb < nkb; kb++) {
    const int k0 = kb * 64;
    __syncthreads();   // prev iteration's LDS reads done
    pf_store();
    __syncthreads();   // tile visible
    if (kb + 1 < nkb) pf_load(k0 + 64);  // overlap with compute

    // ---- S = Q K^T ----
    f32x4 s[4] = {};
#pragma unroll
    for (int kk = 0; kk < 4; kk++) {
      bf16x8 kf[4];
#pragma unroll
      for (int f = 0; f < 4; f++)
        kf[f] = *(const bf16x8*)&Ks[(f * 16 + l16) * KLD + kk * 32 + lg * 8];
#pragma unroll
      for (int f = 0; f < 4; f++)
        s[f] = __builtin_amdgcn_mfma_f32_16x16x32_bf16(qf[kk], kf[f], s[f], 0, 0, 0);
    }
    // ---- softmax (mask only on the diagonal iteration) ----
    float* pw = Ps[wave];
    if (kb == nkb - 1) {
      const int myq = qrow + lg * 4;
#pragma unroll
      for (int f = 0; f < 4; f++)
#pragma unroll
        for (int r = 0; r < 4; r++) {
          int kcol = k0 + f * 16 + l16;
          float p = (kcol <= myq + r) ? exp2f(s[f][r] * C) : 0.0f;
          lsum[r] += p;
          pw[(lg * 4 + r) * PLD + f * 16 + l16] = p;
        }
    } else {
#pragma unroll
      for (int f = 0; f < 4; f++)
#pragma unroll
        for (int r = 0; r < 4; r++) {
          float p = exp2f(s[f][r] * C);
          lsum[r] += p;
          pw[(lg * 4 + r) * PLD + f * 16 + l16] = p;
        }
    }
    __threadfence_block();  // wave-local write->read ordering
    f32x4 pa0 = *(const f32x4*)&pw[l16 * PLD + lg * 8];
    f32x4 pa1 = *(const f32x4*)&pw[l16 * PLD + lg * 8 + 4];
    f32x4 pb0 = *(const f32x4*)&pw[l16 * PLD + 32 + lg * 8];
    f32x4 pb1 = *(const f32x4*)&pw[l16 * PLD + 32 + lg * 8 + 4];
    bf16x8 pfr0 = cvt8(pa0, pa1);
    bf16x8 pfr1 = cvt8(pb0, pb1);
    __threadfence_block();  // reads drain before next iter overwrites
    // ---- O += P V ----
#pragma unroll
    for (int f = 0; f < 8; f++) {
      bf16x8 v0 = *(const bf16x8*)&Vs[(f * 16 + l16) * VLD + lg * 8];
      bf16x8 v1 = *(const bf16x8*)&Vs[(f * 16 + l16) * VLD + 32 + lg * 8];
      o[f] = __builtin_amdgcn_mfma_f32_16x16x32_bf16(pfr0, v0, o[f], 0, 0, 0);
      o[f] = __builtin_amdgcn_mfma_f32_16x16x32_bf16(pfr1, v1, o[f], 0, 0, 0);
    }
  }
  // ---- epilogue ----
  float rl[4];
#pragma unroll
  for (int r = 0; r < 4; r++) {
    float l = lsum[r];
    l += __shfl_xor(l, 1);
    l += __shfl_xor(l, 2);
    l += __shfl_xor(l, 4);
    l += __shfl_xor(l, 8);
    rl[r] = 1.0f / l;
  }
#pragma unroll
  for (int f = 0; f < 8; f++)
#pragma unroll
    for (int r = 0; r < 4; r++) {
      int t = qrow + lg * 4 + r;
      Y[(((size_t)b * T_ + t) * H_ + h) * D_ + f * 16 + l16] = (bf16_t)(o[f][r] * rl[r]);
    }
}

// ---------------------------------------------------------------------------
extern "C" void kernel_launch(void* const* d_in, const int* in_sizes, int n_in,
                              void* d_out, int out_size, void* d_ws, size_t ws_size,
                              hipStream_t stream) {
  (void)in_sizes; (void)n_in; (void)out_size;
  const float* x     = (const float*)d_in[0];
  const float* Wq    = (const float*)d_in[1];
  const float* Wk    = (const float*)d_in[2];
  const float* Wv    = (const float*)d_in[3];
  const float* Wproj = (const float*)d_in[4];
  const float* qgain = (const float*)d_in[5];

  float* out  = (float*)d_out;                  // [B,T,DIM] fp32
  float* vout = out + (size_t)B_ * T_ * DIM_;   // [B,T,HKV,D] fp32

  const size_t M = (size_t)B_ * T_;  // 4096
  char* ws = (char*)d_ws;
  size_t off = 0;
  auto take = [&](size_t elems) { bf16_t* p = (bf16_t*)(ws + off); off += elems * sizeof(bf16_t); return p; };

  bf16_t* Qp = take(M * DIM_);     // Q, later aliased as attention output Y
  bf16_t* Kp = take(M * KVDIM_);
  bf16_t* Vb = take(M * KVDIM_);

  const size_t cvt_elems = M * DIM_ + (size_t)3072 * DIM_ + (size_t)DIM_ * DIM_;
  const bool fast = (ws_size >= off + cvt_elems * sizeof(bf16_t));

  dim3 blk(256);
  if (fast) {
    bf16_t* xb     = take(M * DIM_);
    bf16_t* Wqkvb  = take((size_t)3072 * DIM_);  // Wq | Wk | Wv rows
    bf16_t* Wpb    = take((size_t)DIM_ * DIM_);

    cvt_all<<<dim3(9216), blk, 0, stream>>>(x, Wq, Wk, Wv, Wproj, xb, Wqkvb, Wpb);

    gemm128<1, true, true, DIM_><<<dim3(3072 / 128, M / 128), blk, 0, stream>>>(
        xb, Wqkvb, nullptr, Qp, Kp, Vb, vout, M, 3072);

    qk_norm_rope<<<dim3((unsigned)((M * H_ + M * HKV_) / 4)), blk, 0, stream>>>(Qp, Kp, qgain);
    flash_attn<<<dim3(32, H_, B_), blk, 0, stream>>>(Qp, Kp, Vb, Qp);

    gemm128<2, true, true, DIM_><<<dim3(DIM_ / 128, M / 128), blk, 0, stream>>>(
        Qp, Wpb, nullptr, out, nullptr, nullptr, nullptr, M, DIM_);
  } else {
    gemm128<0, false, false, DIM_><<<dim3(DIM_ / 128, M / 128), blk, 0, stream>>>(
        x, Wq, nullptr, Qp, nullptr, nullptr, nullptr, M, DIM_);
    gemm128<3, false, false, DIM_><<<dim3(2 * KVDIM_ / 128, M / 128), blk, 0, stream>>>(
        x, Wk, Wv, Kp, nullptr, Vb, vout, M, 2 * KVDIM_);
    qk_norm_rope<<<dim3((unsigned)((M * H_ + M * HKV_) / 4)), blk, 0, stream>>>(Qp, Kp, qgain);
    flash_attn<<<dim3(32, H_, B_), blk, 0, stream>>>(Qp, Kp, Vb, Qp);
    gemm128<2, true, false, DIM_><<<dim3(DIM_ / 128, M / 128), blk, 0, stream>>>(
        Qp, Wproj, nullptr, out, nullptr, nullptr, nullptr, M, DIM_);
  }
}